// Round 1
// baseline (612.483 us; speedup 1.0000x reference)
//
#include <hip/hip_runtime.h>
#include <hip/hip_bf16.h>
#include <cstdint>
#include <cstddef>

#define NB 4
#define SEQ 1024
#define HID 768
#define NHEAD 12
#define HD 64

typedef __bf16 bf16x8 __attribute__((ext_vector_type(8)));
typedef float f32x4 __attribute__((ext_vector_type(4)));

__device__ __forceinline__ unsigned short f2bf(float f) {
    unsigned int u = __float_as_uint(f);
    u += 0x7FFFu + ((u >> 16) & 1u);   // round-to-nearest-even
    return (unsigned short)(u >> 16);
}

// ---------------------------------------------------------------------------
// Kernel 1: fused QKV projection GEMM (bf16 MFMA, 128x128 tile, BK=64)
//   z=0: q = (X @ Wq^T + bq) * 0.125  -> qws  [B,NH,S,HD] bf16
//   z=1: k = (X @ Wk^T + bk)          -> kws  [B,NH,S,HD] bf16
//   z=2: v = (X @ Wv^T + bv)          -> vtws [B,NH,HD,S] bf16 (transposed)
// W is [N,K] = exactly the B^T layout the MFMA B-fragment wants.
// ---------------------------------------------------------------------------
__global__ __launch_bounds__(256)
void qkv_kernel(const float* __restrict__ X,
                const float* __restrict__ Wq, const float* __restrict__ bq,
                const float* __restrict__ Wk, const float* __restrict__ bk,
                const float* __restrict__ Wv, const float* __restrict__ bv,
                unsigned short* __restrict__ qws,
                unsigned short* __restrict__ kws,
                unsigned short* __restrict__ vtws)
{
    __shared__ __align__(16) unsigned short Al[128 * 64];
    __shared__ __align__(16) unsigned short Bl[128 * 64];

    const int z = blockIdx.z;
    const float* Wp = (z == 0) ? Wq : ((z == 1) ? Wk : Wv);
    const float* bp = (z == 0) ? bq : ((z == 1) ? bk : bv);
    const int m0 = blockIdx.x * 128;
    const int n0 = blockIdx.y * 128;
    const int t = threadIdx.x;
    const int lane = t & 63;
    const int w = t >> 6;
    const int wm = w >> 1, wn = w & 1;
    const int l15 = lane & 15, l4 = lane >> 4;

    const f32x4 fzero = {0.f, 0.f, 0.f, 0.f};
    f32x4 acc[4][4];
#pragma unroll
    for (int a = 0; a < 4; ++a)
#pragma unroll
        for (int c = 0; c < 4; ++c) acc[a][c] = fzero;

    for (int k0 = 0; k0 < HID; k0 += 64) {
        __syncthreads();
        // stage A (X tile) and B (W tile), converting fp32 -> bf16
#pragma unroll
        for (int i = 0; i < 8; ++i) {
            int idx = t + 256 * i;          // float4 units, 2048 total
            int row = idx >> 4;             // 16 float4 per 64-col row
            int c4  = idx & 15;
            float4 va = *(const float4*)(X + (size_t)(m0 + row) * HID + k0 + c4 * 4);
            ushort4 ua = make_ushort4(f2bf(va.x), f2bf(va.y), f2bf(va.z), f2bf(va.w));
            *(ushort4*)(Al + row * 64 + c4 * 4) = ua;
            float4 vb = *(const float4*)(Wp + (size_t)(n0 + row) * HID + k0 + c4 * 4);
            ushort4 ub = make_ushort4(f2bf(vb.x), f2bf(vb.y), f2bf(vb.z), f2bf(vb.w));
            *(ushort4*)(Bl + row * 64 + c4 * 4) = ub;
        }
        __syncthreads();
#pragma unroll
        for (int kc = 0; kc < 2; ++kc) {
            bf16x8 af[4], bfr[4];
#pragma unroll
            for (int mf = 0; mf < 4; ++mf)
                af[mf] = *(const bf16x8*)(Al + (wm * 64 + mf * 16 + l15) * 64 + kc * 32 + l4 * 8);
#pragma unroll
            for (int nf = 0; nf < 4; ++nf)
                bfr[nf] = *(const bf16x8*)(Bl + (wn * 64 + nf * 16 + l15) * 64 + kc * 32 + l4 * 8);
#pragma unroll
            for (int mf = 0; mf < 4; ++mf)
#pragma unroll
                for (int nf = 0; nf < 4; ++nf)
                    acc[mf][nf] = __builtin_amdgcn_mfma_f32_16x16x32_bf16(
                        af[mf], bfr[nf], acc[mf][nf], 0, 0, 0);
        }
    }

    // epilogue: C/D layout is col = lane&15, row = (lane>>4)*4 + j
#pragma unroll
    for (int nf = 0; nf < 4; ++nf) {
        int n = n0 + wn * 64 + nf * 16 + l15;   // output feature
        float bias = bp[n];
        int h = n >> 6;
        int d = n & 63;
#pragma unroll
        for (int mf = 0; mf < 4; ++mf) {
            int mbase = m0 + wm * 64 + mf * 16 + l4 * 4;  // token row base (j=0..3)
            int bb = mbase >> 10;
            int srow = mbase & 1023;
            if (z == 2) {
                // v transposed: 4 consecutive rows -> 4 consecutive s-cols of vT
                ushort4 u = make_ushort4(f2bf(acc[mf][nf][0] + bias),
                                         f2bf(acc[mf][nf][1] + bias),
                                         f2bf(acc[mf][nf][2] + bias),
                                         f2bf(acc[mf][nf][3] + bias));
                *(ushort4*)(vtws + ((size_t)(bb * NHEAD + h) * HD + d) * SEQ + srow) = u;
            } else {
                float sc = (z == 0) ? 0.125f : 1.0f;
                unsigned short* dst = (z == 0) ? qws : kws;
#pragma unroll
                for (int j = 0; j < 4; ++j)
                    dst[((size_t)(bb * NHEAD + h) * SEQ + srow + j) * HD + d] =
                        f2bf((acc[mf][nf][j] + bias) * sc);
            }
        }
    }
}

// ---------------------------------------------------------------------------
// Kernel 2: flash attention with additive biases + key mask.
// block = (q-tile 64, head, batch), 4 waves, wave owns 16 q-rows.
// KV tile = 64. scores MFMA -> +rel+rel2d -> mask -> online softmax ->
// P via LDS transpose -> PV MFMA (V stored transposed so B-frags are b128).
// ---------------------------------------------------------------------------
__global__ __launch_bounds__(256)
void attn_kernel(const unsigned short* __restrict__ qws,
                 const unsigned short* __restrict__ kws,
                 const unsigned short* __restrict__ vtws,
                 const float* __restrict__ rel,
                 const float* __restrict__ rel2d,
                 const int* __restrict__ mask,
                 float* __restrict__ out)
{
    __shared__ __align__(16) unsigned short Kl[64 * 64];   // [kv][d]
    __shared__ __align__(16) unsigned short Vl[64 * 64];   // [d][kv] (transposed)
    __shared__ __align__(16) unsigned short Pl[4][16 * 64]; // per-wave P [qr][kv]

    const int qt = blockIdx.x;
    const int h  = blockIdx.y;
    const int b  = blockIdx.z;
    const int t = threadIdx.x;
    const int lane = t & 63;
    const int w = t >> 6;
    const int l15 = lane & 15, l4 = lane >> 4;

    const size_t headoff = (size_t)(b * NHEAD + h) * SEQ * HD;
    const unsigned short* qh  = qws + headoff;
    const unsigned short* kh  = kws + headoff;
    const unsigned short* vth = vtws + headoff;    // [64][1024]
    const int q0 = qt * 64 + w * 16;

    // persistent q A-fragments: row = lane&15, k(d) = kc*32 + (lane>>4)*8 + i
    bf16x8 qf[2];
#pragma unroll
    for (int kc = 0; kc < 2; ++kc)
        qf[kc] = *(const bf16x8*)(qh + (size_t)(q0 + l15) * HD + kc * 32 + l4 * 8);

    const f32x4 fzero = {0.f, 0.f, 0.f, 0.f};
    float m_run[4], l_run[4];
    f32x4 acc[4];
#pragma unroll
    for (int j = 0; j < 4; ++j) { m_run[j] = -INFINITY; l_run[j] = 0.f; }
#pragma unroll
    for (int df = 0; df < 4; ++df) acc[df] = fzero;

    const float* relh  = rel   + (size_t)(b * NHEAD + h) * SEQ * SEQ;
    const float* rel2h = rel2d + (size_t)(b * NHEAD + h) * SEQ * SEQ;
    const int* maskb = mask + b * SEQ;

    for (int kv0 = 0; kv0 < SEQ; kv0 += 64) {
        __syncthreads();
        {
            // K tile: contiguous 8KB
            const uint4* srcK = (const uint4*)(kh + (size_t)kv0 * HD);
            ((uint4*)Kl)[t]       = srcK[t];
            ((uint4*)Kl)[t + 256] = srcK[t + 256];
            // V^T tile: 64 rows (d) x 128B from vth
            int u0 = t,       r0 = u0 >> 3, s0 = u0 & 7;
            ((uint4*)Vl)[u0] = *(const uint4*)(vth + (size_t)r0 * SEQ + kv0 + s0 * 8);
            int u1 = t + 256, r1 = u1 >> 3, s1 = u1 & 7;
            ((uint4*)Vl)[u1] = *(const uint4*)(vth + (size_t)r1 * SEQ + kv0 + s1 * 8);
        }
        __syncthreads();

        // scores = q @ k^T : D col = k-col (lane&15), row = q-row ((lane>>4)*4+j)
        f32x4 sacc[4];
#pragma unroll
        for (int nf = 0; nf < 4; ++nf) sacc[nf] = fzero;
#pragma unroll
        for (int kc = 0; kc < 2; ++kc) {
#pragma unroll
            for (int nf = 0; nf < 4; ++nf) {
                bf16x8 kf = *(const bf16x8*)(Kl + (nf * 16 + l15) * 64 + kc * 32 + l4 * 8);
                sacc[nf] = __builtin_amdgcn_mfma_f32_16x16x32_bf16(qf[kc], kf, sacc[nf], 0, 0, 0);
            }
        }

        float p[4][4];
        float tmax[4] = {-INFINITY, -INFINITY, -INFINITY, -INFINITY};
#pragma unroll
        for (int nf = 0; nf < 4; ++nf) {
            int kcol = kv0 + nf * 16 + l15;
            int mv = maskb[kcol];
            const float* r1p = relh  + (size_t)(q0 + l4 * 4) * SEQ + kcol;
            const float* r2p = rel2h + (size_t)(q0 + l4 * 4) * SEQ + kcol;
#pragma unroll
            for (int j = 0; j < 4; ++j) {
                float sv = sacc[nf][j] + r1p[(size_t)j * SEQ] + r2p[(size_t)j * SEQ];
                sv = mv ? -3.402823466e38f : sv;   // mask==1 -> float32 min (ref semantics)
                p[nf][j] = sv;
                tmax[j] = fmaxf(tmax[j], sv);
            }
        }
        // row-wise reduce across the 16 lanes holding the 16 k-cols
#pragma unroll
        for (int j = 0; j < 4; ++j) {
#pragma unroll
            for (int off = 1; off < 16; off <<= 1)
                tmax[j] = fmaxf(tmax[j], __shfl_xor(tmax[j], off, 64));
        }
        float scal[4], tsum[4];
#pragma unroll
        for (int j = 0; j < 4; ++j) {
            float mnew = fmaxf(m_run[j], tmax[j]);
            scal[j] = __expf(m_run[j] - mnew);
            m_run[j] = mnew;
            tsum[j] = 0.f;
        }
#pragma unroll
        for (int nf = 0; nf < 4; ++nf)
#pragma unroll
            for (int j = 0; j < 4; ++j) {
                p[nf][j] = __expf(p[nf][j] - m_run[j]);
                tsum[j] += p[nf][j];
            }
#pragma unroll
        for (int j = 0; j < 4; ++j) {
#pragma unroll
            for (int off = 1; off < 16; off <<= 1)
                tsum[j] += __shfl_xor(tsum[j], off, 64);
            l_run[j] = l_run[j] * scal[j] + tsum[j];
        }
#pragma unroll
        for (int df = 0; df < 4; ++df)
#pragma unroll
            for (int j = 0; j < 4; ++j)
                acc[df][j] *= scal[j];

        // P (D-layout) -> LDS -> A-fragment layout
        unsigned short* Pw = &Pl[w][0];
#pragma unroll
        for (int nf = 0; nf < 4; ++nf)
#pragma unroll
            for (int j = 0; j < 4; ++j)
                Pw[(l4 * 4 + j) * 64 + nf * 16 + l15] = f2bf(p[nf][j]);
        __syncthreads();

        // PV: A = P [16 x 64kv], B = V [kv][d] read from transposed Vl
#pragma unroll
        for (int kc = 0; kc < 2; ++kc) {
            bf16x8 pf = *(const bf16x8*)(Pw + l15 * 64 + kc * 32 + l4 * 8);
#pragma unroll
            for (int df = 0; df < 4; ++df) {
                bf16x8 vf = *(const bf16x8*)(Vl + (df * 16 + l15) * 64 + kc * 32 + l4 * 8);
                acc[df] = __builtin_amdgcn_mfma_f32_16x16x32_bf16(pf, vf, acc[df], 0, 0, 0);
            }
        }
    }

    // epilogue: out[b][s][h*64+d] = acc / l_sum
#pragma unroll
    for (int df = 0; df < 4; ++df) {
        int d = df * 16 + l15;
#pragma unroll
        for (int j = 0; j < 4; ++j) {
            int qr = q0 + l4 * 4 + j;
            out[((size_t)b * SEQ + qr) * HID + h * HD + d] = acc[df][j] / l_run[j];
        }
    }
}

extern "C" void kernel_launch(void* const* d_in, const int* in_sizes, int n_in,
                              void* d_out, int out_size, void* d_ws, size_t ws_size,
                              hipStream_t stream)
{
    const float* hidden = (const float*)d_in[0];
    const int*   amask  = (const int*)d_in[1];
    const float* rel    = (const float*)d_in[2];
    const float* rel2d  = (const float*)d_in[3];
    const float* Wq = (const float*)d_in[4];
    const float* bq = (const float*)d_in[5];
    const float* Wk = (const float*)d_in[6];
    const float* bk = (const float*)d_in[7];
    const float* Wv = (const float*)d_in[8];
    const float* bv = (const float*)d_in[9];
    float* out = (float*)d_out;

    const size_t per = (size_t)NB * NHEAD * SEQ * HD;  // 3,145,728 elems
    unsigned short* qws  = (unsigned short*)d_ws;
    unsigned short* kws  = qws + per;
    unsigned short* vtws = kws + per;

    qkv_kernel<<<dim3(32, 6, 3), 256, 0, stream>>>(hidden, Wq, bq, Wk, bk, Wv, bv,
                                                   qws, kws, vtws);
    attn_kernel<<<dim3(16, 12, 4), 256, 0, stream>>>(qws, kws, vtws, rel, rel2d,
                                                     amask, out);
}

// Round 2
// 490.815 us; speedup vs baseline: 1.2479x; 1.2479x over previous
//
#include <hip/hip_runtime.h>
#include <hip/hip_bf16.h>
#include <cstdint>
#include <cstddef>

#define NB 4
#define SEQ 1024
#define HID 768
#define NHEAD 12
#define HD 64
#define NX (NB * SEQ * HID)   // 3,145,728 floats
#define NW (HID * HID)        // 589,824 floats

typedef __bf16 bf16x8 __attribute__((ext_vector_type(8)));
typedef float f32x4 __attribute__((ext_vector_type(4)));

typedef __attribute__((address_space(3))) void lds_void;
typedef const __attribute__((address_space(1))) void gbl_void;

__device__ __forceinline__ void gload_lds16(const void* gsrc, void* ldst) {
    __builtin_amdgcn_global_load_lds((gbl_void*)gsrc, (lds_void*)ldst, 16, 0, 0);
}

__device__ __forceinline__ unsigned short f2bf(float f) {
    unsigned int u = __float_as_uint(f);
    u += 0x7FFFu + ((u >> 16) & 1u);   // round-to-nearest-even
    return (unsigned short)(u >> 16);
}

// ---------------------------------------------------------------------------
// Kernel 0: fp32 -> bf16 pre-convert of X and [Wq;Wk;Wv] (concatenated)
// ---------------------------------------------------------------------------
__global__ __launch_bounds__(256)
void convert_kernel(const float* __restrict__ X,
                    const float* __restrict__ Wq, const float* __restrict__ Wk,
                    const float* __restrict__ Wv,
                    unsigned short* __restrict__ Xb,
                    unsigned short* __restrict__ Wallb)
{
    int idx = blockIdx.x * 256 + threadIdx.x;   // float4 index
    const int NX4 = NX / 4, NW4 = NW / 4;
    float4 v;
    unsigned short* dst;
    if (idx < NX4) {
        v = ((const float4*)X)[idx];
        dst = Xb + (size_t)idx * 4;
    } else {
        int j = idx - NX4;
        int z = j / NW4;
        int r = j - z * NW4;
        const float* W = (z == 0) ? Wq : ((z == 1) ? Wk : Wv);
        v = ((const float4*)W)[r];
        dst = Wallb + (size_t)z * NW + (size_t)r * 4;
    }
    *(ushort4*)dst = make_ushort4(f2bf(v.x), f2bf(v.y), f2bf(v.z), f2bf(v.w));
}

// ---------------------------------------------------------------------------
// Kernel 1: fused QKV projection GEMM, bf16 inputs, global_load_lds staging.
// N-dim is the concatenation [Wq;Wk;Wv] (2304). 128x128 tile, BK=64.
//   z=0: q*(1/8) -> qws [B,NH,S,HD]   z=1: k -> kws   z=2: v^T -> vtws [B,NH,HD,S]
// ---------------------------------------------------------------------------
__global__ __launch_bounds__(256)
void qkv_kernel(const unsigned short* __restrict__ Xb,
                const unsigned short* __restrict__ Wallb,
                const float* __restrict__ bq, const float* __restrict__ bk,
                const float* __restrict__ bv,
                unsigned short* __restrict__ qws,
                unsigned short* __restrict__ kws,
                unsigned short* __restrict__ vtws)
{
    __shared__ __align__(16) unsigned short Al[128 * 64];
    __shared__ __align__(16) unsigned short Bl[128 * 64];

    const int m0 = blockIdx.x * 128;
    const int n0g = blockIdx.y * 128;          // 0..2176, multiple of 128
    const int t = threadIdx.x;
    const int lane = t & 63;
    const int w = t >> 6;
    const int wm = w >> 1, wn = w & 1;
    const int l15 = lane & 15, l4 = lane >> 4;
    const int rowA = lane >> 3;                 // staging row within 8-row group
    const int cEl = (lane & 7) * 8;             // staging col (elements)

    const f32x4 fzero = {0.f, 0.f, 0.f, 0.f};
    f32x4 acc[4][4];
#pragma unroll
    for (int a = 0; a < 4; ++a)
#pragma unroll
        for (int c = 0; c < 4; ++c) acc[a][c] = fzero;

    for (int k0 = 0; k0 < HID; k0 += 64) {
        __syncthreads();
#pragma unroll
        for (int i = 0; i < 4; ++i) {
            int r = w * 32 + i * 8;
            gload_lds16(Xb + (size_t)(m0 + r + rowA) * HID + k0 + cEl, Al + r * 64);
            gload_lds16(Wallb + (size_t)(n0g + r + rowA) * HID + k0 + cEl, Bl + r * 64);
        }
        __syncthreads();
#pragma unroll
        for (int kc = 0; kc < 2; ++kc) {
            bf16x8 af[4], bfr[4];
#pragma unroll
            for (int mf = 0; mf < 4; ++mf)
                af[mf] = *(const bf16x8*)(Al + (wm * 64 + mf * 16 + l15) * 64 + kc * 32 + l4 * 8);
#pragma unroll
            for (int nf = 0; nf < 4; ++nf)
                bfr[nf] = *(const bf16x8*)(Bl + (wn * 64 + nf * 16 + l15) * 64 + kc * 32 + l4 * 8);
#pragma unroll
            for (int mf = 0; mf < 4; ++mf)
#pragma unroll
                for (int nf = 0; nf < 4; ++nf)
                    acc[mf][nf] = __builtin_amdgcn_mfma_f32_16x16x32_bf16(
                        af[mf], bfr[nf], acc[mf][nf], 0, 0, 0);
        }
    }

    const int z = n0g / HID;                    // 0,1,2 (no tile straddles)
    const int nz0 = n0g - z * HID;
    const float* bp = (z == 0) ? bq : ((z == 1) ? bk : bv);

#pragma unroll
    for (int nf = 0; nf < 4; ++nf) {
        int n = nz0 + wn * 64 + nf * 16 + l15;  // output feature within z
        float bias = bp[n];
        int h = n >> 6;
        int d = n & 63;
#pragma unroll
        for (int mf = 0; mf < 4; ++mf) {
            int mbase = m0 + wm * 64 + mf * 16 + l4 * 4;
            int bb = mbase >> 10;
            int srow = mbase & 1023;
            if (z == 2) {
                ushort4 u = make_ushort4(f2bf(acc[mf][nf][0] + bias),
                                         f2bf(acc[mf][nf][1] + bias),
                                         f2bf(acc[mf][nf][2] + bias),
                                         f2bf(acc[mf][nf][3] + bias));
                *(ushort4*)(vtws + ((size_t)(bb * NHEAD + h) * HD + d) * SEQ + srow) = u;
            } else {
                float sc = (z == 0) ? 0.125f : 1.0f;
                unsigned short* dst = (z == 0) ? qws : kws;
#pragma unroll
                for (int j = 0; j < 4; ++j)
                    dst[((size_t)(bb * NHEAD + h) * SEQ + srow + j) * HD + d] =
                        f2bf((acc[mf][nf][j] + bias) * sc);
            }
        }
    }
}

// ---------------------------------------------------------------------------
// Kernel 2: flash attention, swapped-operand MFMAs.
//   QK^T = mfma(K, Q): D col=q(lane&15), row=kv((lane>>4)*4+j)+nf*16
//     -> bias/mask are per-lane float4/int4 loads, softmax rows lane-local.
//   PV = mfma(V^T, P): D col=q(lane&15), row=d
// K/V staged via global_load_lds with pre-swizzled source (XOR bank swizzle),
// double-buffered; P through per-wave swizzled LDS.
// ---------------------------------------------------------------------------
__device__ __forceinline__ void stage_kv(const unsigned short* kh,
                                         const unsigned short* vth,
                                         unsigned short* Kd, unsigned short* Vd,
                                         int kv0, int w, int lane)
{
    int r8 = lane >> 3;
    int swzB = (((lane & 7) ^ r8) * 16);     // pre-swizzled 16B slot
#pragma unroll
    for (int i = 0; i < 2; ++i) {
        int rb = w * 16 + i * 8;
        gload_lds16((const char*)(kh + (size_t)(kv0 + rb + r8) * HD) + swzB,
                    Kd + rb * 64);
        gload_lds16((const char*)(vth + (size_t)(rb + r8) * SEQ + kv0) + swzB,
                    Vd + rb * 64);
    }
}

__device__ __forceinline__ const bf16x8* swz_rd(const unsigned short* base, int row, int colbyte) {
    int phys = (row * 128 + colbyte) ^ ((row & 7) << 4);
    return (const bf16x8*)((const char*)base + phys);
}

__global__ __launch_bounds__(256)
void attn_kernel(const unsigned short* __restrict__ qws,
                 const unsigned short* __restrict__ kws,
                 const unsigned short* __restrict__ vtws,
                 const float* __restrict__ rel,
                 const float* __restrict__ rel2d,
                 const int* __restrict__ mask,
                 float* __restrict__ out)
{
    __shared__ __align__(16) unsigned short Kl[2][64 * 64];
    __shared__ __align__(16) unsigned short Vl[2][64 * 64];
    __shared__ __align__(16) unsigned short Pl[4][16 * 64];

    const int qt = blockIdx.x;
    const int h  = blockIdx.y;
    const int b  = blockIdx.z;
    const int t = threadIdx.x;
    const int lane = t & 63;
    const int w = t >> 6;
    const int l15 = lane & 15, l4 = lane >> 4;

    const size_t headoff = (size_t)(b * NHEAD + h) * SEQ * HD;
    const unsigned short* qh  = qws + headoff;
    const unsigned short* kh  = kws + headoff;
    const unsigned short* vth = vtws + headoff;
    const int q0 = qt * 64 + w * 16;
    const int qrow = q0 + l15;                  // this lane's softmax row

    bf16x8 qf[2];
#pragma unroll
    for (int kc = 0; kc < 2; ++kc)
        qf[kc] = *(const bf16x8*)(qh + (size_t)qrow * HD + kc * 32 + l4 * 8);

    const f32x4 fzero = {0.f, 0.f, 0.f, 0.f};
    float m_run = -INFINITY, l_run = 0.f;
    f32x4 acc[4];
#pragma unroll
    for (int df = 0; df < 4; ++df) acc[df] = fzero;

    const float* r1base = rel   + ((size_t)(b * NHEAD + h) * SEQ + qrow) * SEQ + l4 * 4;
    const float* r2base = rel2d + ((size_t)(b * NHEAD + h) * SEQ + qrow) * SEQ + l4 * 4;
    const int* mb4 = mask + b * SEQ + l4 * 4;
    unsigned short* Pw = Pl[w];

    stage_kv(kh, vth, Kl[0], Vl[0], 0, w, lane);
    int cur = 0;

    for (int tt = 0; tt < 16; ++tt) {
        const int kv0 = tt * 64;
        __syncthreads();                           // staged buf[cur] landed
        if (tt < 15)
            stage_kv(kh, vth, Kl[cur ^ 1], Vl[cur ^ 1], kv0 + 64, w, lane);

        // issue bias + mask loads early (overlap with MFMA)
        float4 b1[4], b2[4];
        int4 mv[4];
#pragma unroll
        for (int nf = 0; nf < 4; ++nf) {
            b1[nf] = *(const float4*)(r1base + kv0 + nf * 16);
            b2[nf] = *(const float4*)(r2base + kv0 + nf * 16);
            mv[nf] = *(const int4*)(mb4 + kv0 + nf * 16);
        }

        const unsigned short* Kc = Kl[cur];
        const unsigned short* Vc = Vl[cur];
        f32x4 sacc[4];
#pragma unroll
        for (int nf = 0; nf < 4; ++nf) sacc[nf] = fzero;
#pragma unroll
        for (int kc = 0; kc < 2; ++kc) {
#pragma unroll
            for (int nf = 0; nf < 4; ++nf) {
                bf16x8 kf = *swz_rd(Kc, nf * 16 + l15, kc * 64 + l4 * 16);
                sacc[nf] = __builtin_amdgcn_mfma_f32_16x16x32_bf16(kf, qf[kc], sacc[nf], 0, 0, 0);
            }
        }

        // scores + bias + mask, lane-local softmax row
        float pv[4][4];
        float tmax = -INFINITY;
#pragma unroll
        for (int nf = 0; nf < 4; ++nf) {
            float bx[4] = {b1[nf].x + b2[nf].x, b1[nf].y + b2[nf].y,
                           b1[nf].z + b2[nf].z, b1[nf].w + b2[nf].w};
            int mm[4] = {mv[nf].x, mv[nf].y, mv[nf].z, mv[nf].w};
#pragma unroll
            for (int j = 0; j < 4; ++j) {
                float sv = mm[j] ? -3.402823466e38f : (sacc[nf][j] + bx[j]);
                pv[nf][j] = sv;
                tmax = fmaxf(tmax, sv);
            }
        }
        tmax = fmaxf(tmax, __shfl_xor(tmax, 16, 64));
        tmax = fmaxf(tmax, __shfl_xor(tmax, 32, 64));

        float mnew = fmaxf(m_run, tmax);
        float scal = __expf(m_run - mnew);
        m_run = mnew;
        float tsum = 0.f;
#pragma unroll
        for (int nf = 0; nf < 4; ++nf)
#pragma unroll
            for (int j = 0; j < 4; ++j) {
                pv[nf][j] = __expf(pv[nf][j] - mnew);
                tsum += pv[nf][j];
            }
        tsum += __shfl_xor(tsum, 16, 64);
        tsum += __shfl_xor(tsum, 32, 64);
        l_run = l_run * scal + tsum;
#pragma unroll
        for (int df = 0; df < 4; ++df)
#pragma unroll
            for (int j = 0; j < 4; ++j) acc[df][j] *= scal;

        // P -> per-wave LDS (swizzled ushort4 stores), layout [q=16][kv=64]
#pragma unroll
        for (int nf = 0; nf < 4; ++nf) {
            ushort4 u = make_ushort4(f2bf(pv[nf][0]), f2bf(pv[nf][1]),
                                     f2bf(pv[nf][2]), f2bf(pv[nf][3]));
            int linb = l15 * 128 + nf * 32 + l4 * 8;
            *(ushort4*)((char*)Pw + (linb ^ ((l15 & 7) << 4))) = u;
        }

        // PV: mfma(V^T, P) -> acc[df] holds d=df*16+l4*4+j, q=l15
#pragma unroll
        for (int kc = 0; kc < 2; ++kc) {
            bf16x8 pf = *swz_rd(Pw, l15, kc * 64 + l4 * 16);
#pragma unroll
            for (int df = 0; df < 4; ++df) {
                bf16x8 vf = *swz_rd(Vc, df * 16 + l15, kc * 64 + l4 * 16);
                acc[df] = __builtin_amdgcn_mfma_f32_16x16x32_bf16(vf, pf, acc[df], 0, 0, 0);
            }
        }
        cur ^= 1;
    }

    // epilogue: out[b][qrow][h*64 + d], float4 per df
    const float inv_l = 1.0f / l_run;
    float* ob = out + ((size_t)b * SEQ + qrow) * HID + h * HD + l4 * 4;
#pragma unroll
    for (int df = 0; df < 4; ++df) {
        float4 o = make_float4(acc[df][0] * inv_l, acc[df][1] * inv_l,
                               acc[df][2] * inv_l, acc[df][3] * inv_l);
        *(float4*)(ob + df * 16) = o;
    }
}

extern "C" void kernel_launch(void* const* d_in, const int* in_sizes, int n_in,
                              void* d_out, int out_size, void* d_ws, size_t ws_size,
                              hipStream_t stream)
{
    const float* hidden = (const float*)d_in[0];
    const int*   amask  = (const int*)d_in[1];
    const float* rel    = (const float*)d_in[2];
    const float* rel2d  = (const float*)d_in[3];
    const float* Wq = (const float*)d_in[4];
    const float* bq = (const float*)d_in[5];
    const float* Wk = (const float*)d_in[6];
    const float* bk = (const float*)d_in[7];
    const float* Wv = (const float*)d_in[8];
    const float* bv = (const float*)d_in[9];
    float* out = (float*)d_out;

    const size_t per = (size_t)NB * NHEAD * SEQ * HD;   // 3,145,728
    unsigned short* qws   = (unsigned short*)d_ws;
    unsigned short* kws   = qws + per;
    unsigned short* vtws  = kws + per;
    unsigned short* Xb    = vtws + per;
    unsigned short* Wallb = Xb + (size_t)NX;

    convert_kernel<<<dim3((NX + 3 * NW) / 1024), 256, 0, stream>>>(
        hidden, Wq, Wk, Wv, Xb, Wallb);
    qkv_kernel<<<dim3(32, 18), 256, 0, stream>>>(Xb, Wallb, bq, bk, bv,
                                                 qws, kws, vtws);
    attn_kernel<<<dim3(16, NHEAD, NB), 256, 0, stream>>>(qws, kws, vtws, rel, rel2d,
                                                         amask, out);
}